// Round 1
// baseline (26.542 us; speedup 1.0000x reference)
//
#include <hip/hip_runtime.h>
#include <math.h>

#define NPATCH 196   // 14*14 patches per image
#define NIMG_THREADS 256

__global__ __launch_bounds__(256) void quanv_fused(
    const float* __restrict__ x,      // [N,1,28,28]
    const float* __restrict__ U_re,   // [16,16]
    const float* __restrict__ U_im,   // [16,16]
    const float* __restrict__ W,      // [10,784]
    const float* __restrict__ bias,   // [10]
    float* __restrict__ out)          // [N,10]
{
    __shared__ float sfeat[784];
    __shared__ float swred[4][10];
    __shared__ float slog[10];

    const int img = blockIdx.x;
    const int tid = threadIdx.x;
    const float* xi = x + (size_t)img * 784;

    if (tid < NPATCH) {
        const int pr = tid / 14;
        const int pc = tid - pr * 14;
        // 2x2 patch, row-major pixels -> wires 0..3
        const float2 r0 = *(const float2*)(xi + (2 * pr) * 28 + 2 * pc);
        const float2 r1 = *(const float2*)(xi + (2 * pr + 1) * 28 + 2 * pc);
        float s0, c0, s1, c1, s2, c2, s3, c3;
        __sincosf(r0.x * 0.5f, &s0, &c0);
        __sincosf(r0.y * 0.5f, &s1, &c1);
        __sincosf(r1.x * 0.5f, &s2, &c2);
        __sincosf(r1.y * 0.5f, &s3, &c3);
        // psi = (v0 (x) v1) (x) (v2 (x) v3), wire0 = MSB
        const float a0 = c0 * c1, a1 = c0 * s1, a2 = s0 * c1, a3 = s0 * s1;
        const float b0 = c2 * c3, b1 = c2 * s3, b2 = s2 * c3, b3 = s2 * s3;
        float psi[16];
        psi[0]  = a0 * b0; psi[1]  = a0 * b1; psi[2]  = a0 * b2; psi[3]  = a0 * b3;
        psi[4]  = a1 * b0; psi[5]  = a1 * b1; psi[6]  = a1 * b2; psi[7]  = a1 * b3;
        psi[8]  = a2 * b0; psi[9]  = a2 * b1; psi[10] = a2 * b2; psi[11] = a2 * b3;
        psi[12] = a3 * b0; psi[13] = a3 * b1; psi[14] = a3 * b2; psi[15] = a3 * b3;

        float z0 = 0.f, z1 = 0.f, z2 = 0.f, z3 = 0.f;
        #pragma unroll
        for (int j = 0; j < 16; ++j) {
            const float4* Ur = (const float4*)(U_re + j * 16);
            const float4* Ui = (const float4*)(U_im + j * 16);
            float re = 0.f, im = 0.f;
            #pragma unroll
            for (int q = 0; q < 4; ++q) {
                const float4 ur = Ur[q];
                const float4 ui = Ui[q];
                re = fmaf(ur.x, psi[q * 4 + 0], re);
                re = fmaf(ur.y, psi[q * 4 + 1], re);
                re = fmaf(ur.z, psi[q * 4 + 2], re);
                re = fmaf(ur.w, psi[q * 4 + 3], re);
                im = fmaf(ui.x, psi[q * 4 + 0], im);
                im = fmaf(ui.y, psi[q * 4 + 1], im);
                im = fmaf(ui.z, psi[q * 4 + 2], im);
                im = fmaf(ui.w, psi[q * 4 + 3], im);
            }
            const float p = re * re + im * im;
            // PauliZ: wire w <-> bit (3-w); compile-time sign after unroll
            z0 += (j & 8) ? -p : p;
            z1 += (j & 4) ? -p : p;
            z2 += (j & 2) ? -p : p;
            z3 += (j & 1) ? -p : p;
        }
        sfeat[tid * 4 + 0] = z0;
        sfeat[tid * 4 + 1] = z1;
        sfeat[tid * 4 + 2] = z2;
        sfeat[tid * 4 + 3] = z3;
    }
    __syncthreads();

    // logits: [10,784] @ feats[784]
    float acc[10];
    #pragma unroll
    for (int c = 0; c < 10; ++c) acc[c] = 0.f;
    for (int f = tid; f < 784; f += NIMG_THREADS) {
        const float fv = sfeat[f];
        #pragma unroll
        for (int c = 0; c < 10; ++c) acc[c] = fmaf(W[c * 784 + f], fv, acc[c]);
    }
    // wave (64-lane) shuffle reduce
    #pragma unroll
    for (int c = 0; c < 10; ++c) {
        #pragma unroll
        for (int off = 32; off > 0; off >>= 1)
            acc[c] += __shfl_down(acc[c], off, 64);
    }
    const int wid = tid >> 6;
    const int lane = tid & 63;
    if (lane == 0) {
        #pragma unroll
        for (int c = 0; c < 10; ++c) swred[wid][c] = acc[c];
    }
    __syncthreads();
    if (tid < 10) {
        slog[tid] = bias[tid] + swred[0][tid] + swred[1][tid] + swred[2][tid] + swred[3][tid];
    }
    __syncthreads();
    if (tid < 10) {
        float m = slog[0];
        #pragma unroll
        for (int i = 1; i < 10; ++i) m = fmaxf(m, slog[i]);
        float s = 0.f;
        #pragma unroll
        for (int i = 0; i < 10; ++i) s += expf(slog[i] - m);
        out[(size_t)img * 10 + tid] = slog[tid] - m - logf(s);
    }
}

extern "C" void kernel_launch(void* const* d_in, const int* in_sizes, int n_in,
                              void* d_out, int out_size, void* d_ws, size_t ws_size,
                              hipStream_t stream) {
    const float* x    = (const float*)d_in[0];
    const float* U_re = (const float*)d_in[1];
    const float* U_im = (const float*)d_in[2];
    const float* W    = (const float*)d_in[3];
    const float* bias = (const float*)d_in[4];
    float* out = (float*)d_out;
    const int n = in_sizes[0] / 784;  // 4096 images
    quanv_fused<<<n, NIMG_THREADS, 0, stream>>>(x, U_re, U_im, W, bias, out);
}